// Round 6
// baseline (7028.008 us; speedup 1.0000x reference)
//
#include <hip/hip_runtime.h>
#include <math.h>

#define B_  64
#define T_  150
#define L_  256
#define H_  512
#define E_  512
#define V_  1000
#define G4_ 2048   // 4*H
#define NBLK 256   // one block per CU; NBLK*JC == H_ (full h-column coverage!)
#define JC  2      // h-columns owned per block

__device__ __forceinline__ float sigmf(float x) { return 1.0f / (1.0f + expf(-x)); }

// ---------------- device-scope grid barrier ----------------
__device__ __forceinline__ void gridbar(int* cnt, int tgt)
{
    __syncthreads();
    if (threadIdx.x == 0) {
        __threadfence();   // release: my h writes -> coherence point
        __hip_atomic_fetch_add(cnt, 1, __ATOMIC_RELAXED, __HIP_MEMORY_SCOPE_AGENT);
        while (__hip_atomic_load(cnt, __ATOMIC_RELAXED, __HIP_MEMORY_SCOPE_AGENT)
               < NBLK * tgt)
            __builtin_amdgcn_s_sleep(2);
        __threadfence();   // acquire: drop stale lines before reading others' h
    }
    __syncthreads();
}

// ---------------- persistent serial LSTM recurrence ----------------
// 256 blocks x 256 threads. Block owns h-cols {j0, j0+1} (JC=2) -> 8 gate rows
// (4 gates x 2 cols), weights LDS-resident. h global layout [B][H] (float4-able).
// Thread (lane = q*16+bq, wave = ks): gate-q, cols j0..j0+1, b in {bq*4..bq*4+3},
// k in [ks*128, ks*128+128). Register tile 2x4; k-split partials reduced via LDS.
__global__ __launch_bounds__(256) void decoder_persistent(
    const int*   __restrict__ seq,    // [B][T]
    const float* __restrict__ G,      // [V][4H] pregate table
    const float* __restrict__ Whh,    // [4H][H] original layout
    float* hA, float* hB,             // [B][H] double buffer
    float* __restrict__ hbuf,         // rows (t,b): [T*B][H]
    int* cnt)
{
    const int tid  = threadIdx.x;
    const int bid  = blockIdx.x;
    const int ks   = tid >> 6;         // k-slice 0..3
    const int lane = tid & 63;
    const int q    = lane >> 4;        // gate 0..3 (i,f,g,o)
    const int bq   = lane & 15;        // b-quad
    const int j0   = bid * JC;

    __shared__ __align__(16) float wl[4 * JC][516];     // [q*JC+jc][k], pad 4
    __shared__ __align__(16) float red[4][4][JC][68];   // [ks][q][jc][b], pad 4
    __shared__ float csh[JC][64];

    // one-time: weight rows (q*512 + j0 + jc) -> LDS (contiguous 2 KB rows)
    for (int e = tid; e < 4 * JC * 512; e += 256) {
        int k = e & 511, r = e >> 9;             // r = qq*JC + jc
        int qq = r >> 1, jc = r & 1;
        wl[r][k] = Whh[(size_t)(qq * H_ + j0 + jc) * H_ + k];
    }
    // zero h0 (blocks 0..127 cover B*H = 32768 elements)
    {
        int zi = bid * 256 + tid;
        if (zi < B_ * H_) hA[zi] = 0.f;
    }
    if (tid < JC * 64) csh[tid >> 6][tid & 63] = 0.f;

    const int jc_f = tid >> 6, b_f = tid & 63;   // finalize mapping (tid < 128)
    float gq[4];
    if (tid < JC * 64) {
        const int v = seq[b_f * T_ + 0];
        #pragma unroll
        for (int qq = 0; qq < 4; ++qq)
            gq[qq] = G[(size_t)v * G4_ + qq * H_ + j0 + jc_f];
    }
    gridbar(cnt, 1);

    for (int t = 0; t < T_; ++t) {
        const float* hc = (t & 1) ? hB : hA;
        float*       hn = (t & 1) ? hA : hB;

        // ---- register-tiled matvec: acc[jc][bb] over 128-k slice
        float acc[JC][4] = {};
        const int kb = ks * 128;
        const float* wp0 = &wl[q * JC + 0][kb];
        const float* wp1 = &wl[q * JC + 1][kb];
        const float* hp  = hc + kb;
        #pragma unroll 4
        for (int kq = 0; kq < 128; kq += 4) {
            float4 w0 = *(const float4*)(wp0 + kq);
            float4 w1 = *(const float4*)(wp1 + kq);
            #pragma unroll
            for (int bb = 0; bb < 4; ++bb) {
                float4 hv = *(const float4*)(hp + (size_t)(bq * 4 + bb) * H_ + kq);
                acc[0][bb] += w0.x * hv.x + w0.y * hv.y + w0.z * hv.z + w0.w * hv.w;
                acc[1][bb] += w1.x * hv.x + w1.y * hv.y + w1.z * hv.z + w1.w * hv.w;
            }
        }
        *(float4*)&red[ks][q][0][bq * 4] = make_float4(acc[0][0], acc[0][1], acc[0][2], acc[0][3]);
        *(float4*)&red[ks][q][1][bq * 4] = make_float4(acc[1][0], acc[1][1], acc[1][2], acc[1][3]);
        __syncthreads();

        // ---- finalize: reduce k-slices, apply cell (threads 0..127)
        if (tid < JC * 64) {
            float g[4];
            #pragma unroll
            for (int qq = 0; qq < 4; ++qq)
                g[qq] = red[0][qq][jc_f][b_f] + red[1][qq][jc_f][b_f]
                      + red[2][qq][jc_f][b_f] + red[3][qq][jc_f][b_f] + gq[qq];
            float c2 = sigmf(g[1]) * csh[jc_f][b_f] + sigmf(g[0]) * tanhf(g[2]);
            float h2 = sigmf(g[3]) * tanhf(c2);
            csh[jc_f][b_f] = c2;
            hn[(size_t)b_f * H_ + j0 + jc_f] = h2;
            hbuf[((size_t)t * 64 + b_f) * H_ + j0 + jc_f] = h2;
            // prefetch next step's pregate (read-only; hides under barrier wait)
            if (t + 1 < T_) {
                const int v = seq[b_f * T_ + t + 1];
                #pragma unroll
                for (int qq = 0; qq < 4; ++qq)
                    gq[qq] = G[(size_t)v * G4_ + qq * H_ + j0 + jc_f];
            }
        }
        gridbar(cnt, t + 2);
    }
}

// ---------------- generic NT GEMM: C[M][N] = op(A[M][K]) @ B[N][K]^T (+bias)
template<bool RELU_A, bool REMAP>
__global__ __launch_bounds__(256) void gemm_nt(
    const float* __restrict__ A, size_t lda, size_t azs,
    const float* __restrict__ Bm, size_t ldb, size_t bzs,
    const float* __restrict__ bias1, const float* __restrict__ bias2,
    float* __restrict__ C, size_t ldc, size_t czs, int M, int N, int K)
{
    A  += blockIdx.z * azs;
    Bm += blockIdx.z * bzs;
    C  += blockIdx.z * czs;
    __shared__ __align__(16) float As[16][68];
    __shared__ __align__(16) float Bs[16][68];
    const int tid = threadIdx.x;
    const int m0 = blockIdx.x * 64;
    const int n0 = blockIdx.y * 64;
    const int lr = tid >> 2;
    const int lc = (tid & 3) << 2;
    const int tm = (tid & 15) << 2;
    const int tn = (tid >> 4) << 2;
    float acc[4][4] = {};

    for (int kb = 0; kb < K; kb += 16) {
        float4 a4 = make_float4(0.f, 0.f, 0.f, 0.f);
        int gm = m0 + lr;
        if (gm < M) a4 = *(const float4*)(A + (size_t)gm * lda + kb + lc);
        if (RELU_A) {
            a4.x = fmaxf(a4.x, 0.f); a4.y = fmaxf(a4.y, 0.f);
            a4.z = fmaxf(a4.z, 0.f); a4.w = fmaxf(a4.w, 0.f);
        }
        As[lc + 0][lr] = a4.x; As[lc + 1][lr] = a4.y;
        As[lc + 2][lr] = a4.z; As[lc + 3][lr] = a4.w;

        float4 b4 = make_float4(0.f, 0.f, 0.f, 0.f);
        int gn = n0 + lr;
        if (gn < N) b4 = *(const float4*)(Bm + (size_t)gn * ldb + kb + lc);
        Bs[lc + 0][lr] = b4.x; Bs[lc + 1][lr] = b4.y;
        Bs[lc + 2][lr] = b4.z; Bs[lc + 3][lr] = b4.w;
        __syncthreads();

        #pragma unroll
        for (int k = 0; k < 16; ++k) {
            float4 av = *(const float4*)&As[k][tm];
            float4 bv = *(const float4*)&Bs[k][tn];
            float af[4] = {av.x, av.y, av.z, av.w};
            float bf[4] = {bv.x, bv.y, bv.z, bv.w};
            #pragma unroll
            for (int i = 0; i < 4; ++i)
                #pragma unroll
                for (int j = 0; j < 4; ++j)
                    acc[i][j] += af[i] * bf[j];
        }
        __syncthreads();
    }

    #pragma unroll
    for (int i = 0; i < 4; ++i) {
        int gm = m0 + tm + i;
        if (gm >= M) continue;
        size_t row = REMAP ? ((size_t)(gm & 63) * T_ + (gm >> 6)) : (size_t)gm;
        #pragma unroll
        for (int j = 0; j < 4; ++j) {
            int gn = n0 + tn + j;
            if (gn >= N) continue;
            float v = acc[i][j];
            if (bias1) v += bias1[gn];
            if (bias2) v += bias2[gn];
            C[row * ldc + gn] = v;
        }
    }
}

// ---------------- dual-A NT GEMM: C[M][N] = [A1|A2] @ Bm[N][1024]^T
__global__ __launch_bounds__(256) void gemm_cat(
    const float* __restrict__ A1, const float* __restrict__ A2,
    const float* __restrict__ Bm, float* __restrict__ C, int M, int N)
{
    __shared__ __align__(16) float As[16][68];
    __shared__ __align__(16) float Bs[16][68];
    const int tid = threadIdx.x;
    const int m0 = blockIdx.x * 64;
    const int n0 = blockIdx.y * 64;
    const int lr = tid >> 2;
    const int lc = (tid & 3) << 2;
    const int tm = (tid & 15) << 2;
    const int tn = (tid >> 4) << 2;
    float acc[4][4] = {};

    for (int kb = 0; kb < 1024; kb += 16) {
        const float* Asel = (kb < 512) ? A1 : A2;
        int kk = kb & 511;
        float4 a4 = make_float4(0.f, 0.f, 0.f, 0.f);
        int gm = m0 + lr;
        if (gm < M) a4 = *(const float4*)(Asel + (size_t)gm * 512 + kk + lc);
        As[lc + 0][lr] = a4.x; As[lc + 1][lr] = a4.y;
        As[lc + 2][lr] = a4.z; As[lc + 3][lr] = a4.w;

        float4 b4 = make_float4(0.f, 0.f, 0.f, 0.f);
        int gn = n0 + lr;
        if (gn < N) b4 = *(const float4*)(Bm + (size_t)gn * 1024 + kb + lc);
        Bs[lc + 0][lr] = b4.x; Bs[lc + 1][lr] = b4.y;
        Bs[lc + 2][lr] = b4.z; Bs[lc + 3][lr] = b4.w;
        __syncthreads();

        #pragma unroll
        for (int k = 0; k < 16; ++k) {
            float4 av = *(const float4*)&As[k][tm];
            float4 bv = *(const float4*)&Bs[k][tn];
            float af[4] = {av.x, av.y, av.z, av.w};
            float bf[4] = {bv.x, bv.y, bv.z, bv.w};
            #pragma unroll
            for (int i = 0; i < 4; ++i)
                #pragma unroll
                for (int j = 0; j < 4; ++j)
                    acc[i][j] += af[i] * bf[j];
        }
        __syncthreads();
    }

    #pragma unroll
    for (int i = 0; i < 4; ++i) {
        int gm = m0 + tm + i;
        if (gm >= M) continue;
        #pragma unroll
        for (int j = 0; j < 4; ++j) {
            int gn = n0 + tn + j;
            if (gn >= N) continue;
            C[(size_t)gm * N + gn] = acc[i][j];
        }
    }
}

// ---------------- NN GEMM: C[M][N] = A[M][K] @ B[K][N]  (ctx = att @ cnn)
__global__ __launch_bounds__(256) void gemm_nn(
    const float* __restrict__ A, size_t lda, size_t azs,
    const float* __restrict__ Bm, size_t ldb, size_t bzs,
    float* __restrict__ C, size_t ldc, size_t czs, int M, int N, int K)
{
    A  += blockIdx.z * azs;
    Bm += blockIdx.z * bzs;
    C  += blockIdx.z * czs;
    __shared__ __align__(16) float As[16][68];
    __shared__ __align__(16) float Bs[16][68];
    const int tid = threadIdx.x;
    const int m0 = blockIdx.x * 64;
    const int n0 = blockIdx.y * 64;
    const int lr = tid >> 2;
    const int lc = (tid & 3) << 2;
    const int br = tid >> 4;
    const int bc = (tid & 15) << 2;
    const int tm = (tid & 15) << 2;
    const int tn = (tid >> 4) << 2;
    float acc[4][4] = {};

    for (int kb = 0; kb < K; kb += 16) {
        float4 a4 = make_float4(0.f, 0.f, 0.f, 0.f);
        int gm = m0 + lr;
        if (gm < M) a4 = *(const float4*)(A + (size_t)gm * lda + kb + lc);
        As[lc + 0][lr] = a4.x; As[lc + 1][lr] = a4.y;
        As[lc + 2][lr] = a4.z; As[lc + 3][lr] = a4.w;

        float4 b4 = make_float4(0.f, 0.f, 0.f, 0.f);
        if (n0 + bc < N) b4 = *(const float4*)(Bm + (size_t)(kb + br) * ldb + n0 + bc);
        Bs[br][bc + 0] = b4.x; Bs[br][bc + 1] = b4.y;
        Bs[br][bc + 2] = b4.z; Bs[br][bc + 3] = b4.w;
        __syncthreads();

        #pragma unroll
        for (int k = 0; k < 16; ++k) {
            float4 av = *(const float4*)&As[k][tm];
            float4 bv = *(const float4*)&Bs[k][tn];
            float af[4] = {av.x, av.y, av.z, av.w};
            float bf[4] = {bv.x, bv.y, bv.z, bv.w};
            #pragma unroll
            for (int i = 0; i < 4; ++i)
                #pragma unroll
                for (int j = 0; j < 4; ++j)
                    acc[i][j] += af[i] * bf[j];
        }
        __syncthreads();
    }

    #pragma unroll
    for (int i = 0; i < 4; ++i) {
        int gm = m0 + tm + i;
        if (gm >= M) continue;
        #pragma unroll
        for (int j = 0; j < 4; ++j) {
            int gn = n0 + tn + j;
            if (gn >= N) continue;
            C[(size_t)gm * ldc + gn] = acc[i][j];
        }
    }
}

// ---------------- softmax over rows of 256 (attention weights), 4 rows/block
__global__ __launch_bounds__(256) void att_softmax(float* __restrict__ att, int nrows)
{
    const int tid = threadIdx.x, lane = tid & 63, wave = tid >> 6;
    const int row = blockIdx.x * 4 + wave;
    if (row >= nrows) return;
    float4* p = (float4*)(att + (size_t)row * L_);
    float4 sc = p[lane];
    float mx = fmaxf(fmaxf(sc.x, sc.y), fmaxf(sc.z, sc.w));
    #pragma unroll
    for (int off = 32; off; off >>= 1) mx = fmaxf(mx, __shfl_xor(mx, off));
    float e0 = expf(sc.x - mx), e1 = expf(sc.y - mx);
    float e2 = expf(sc.z - mx), e3 = expf(sc.w - mx);
    float s = e0 + e1 + e2 + e3;
    #pragma unroll
    for (int off = 32; off; off >>= 1) s += __shfl_xor(s, off);
    float inv = 1.f / s;
    p[lane] = make_float4(e0 * inv, e1 * inv, e2 * inv, e3 * inv);
}

// ---------------- per-row log_softmax over V=1000, in place
__global__ __launch_bounds__(256) void logsoftmax_k(float* __restrict__ out)
{
    const int row = blockIdx.x;
    float* p = out + (size_t)row * V_;
    const int tid = threadIdx.x, lane = tid & 63, wave = tid >> 6;
    __shared__ float red[8];

    float vals[4];
    int n = 0;
    float mx = -INFINITY;
    for (int v = tid; v < V_; v += 256) { vals[n] = p[v]; mx = fmaxf(mx, vals[n]); ++n; }
    #pragma unroll
    for (int off = 32; off; off >>= 1) mx = fmaxf(mx, __shfl_xor(mx, off));
    if (lane == 0) red[wave] = mx;
    __syncthreads();
    mx = fmaxf(fmaxf(red[0], red[1]), fmaxf(red[2], red[3]));

    float s = 0.f;
    for (int i = 0; i < n; ++i) s += expf(vals[i] - mx);
    #pragma unroll
    for (int off = 32; off; off >>= 1) s += __shfl_xor(s, off);
    if (lane == 0) red[4 + wave] = s;
    __syncthreads();
    s = red[4] + red[5] + red[6] + red[7];

    const float lse = mx + logf(s);
    n = 0;
    for (int v = tid; v < V_; v += 256) { p[v] = vals[n] - lse; ++n; }
}

extern "C" void kernel_launch(void* const* d_in, const int* in_sizes, int n_in,
                              void* d_out, int out_size, void* d_ws, size_t ws_size,
                              hipStream_t stream)
{
    const float* cnn     = (const float*)d_in[0];
    const int*   seq     = (const int*)d_in[1];
    const float* embed   = (const float*)d_in[2];
    const float* W_ih    = (const float*)d_in[3];
    const float* b_ih    = (const float*)d_in[4];
    const float* W_hh    = (const float*)d_in[5];
    const float* b_hh    = (const float*)d_in[6];
    const float* W_hm    = (const float*)d_in[7];
    const float* W_om    = (const float*)d_in[8];
    const float* W_logit = (const float*)d_in[9];
    const float* b_logit = (const float*)d_in[10];
    float* out = (float*)d_out;

    float* ws = (float*)d_ws;
    float* G    = ws;                                  // 1000*2048 = 2,048,000
    float* hT_a = G + (size_t)V_ * G4_;                // [B][H]
    float* hT_b = hT_a + (size_t)H_ * B_;
    float* hbuf = hT_b + (size_t)H_ * B_;              // 9600*512 (rows (t,b))
    float* outv = hbuf + (size_t)B_ * T_ * H_;         // 9600*512
    int*   cnt  = (int*)(outv + (size_t)B_ * T_ * H_);
    // scratch inside d_out (dead before the final logits write):
    float* mapped = out;                               // 9600*512; reused as ctx
    float* attb   = out + (size_t)B_ * T_ * H_;        // 9600*256

    hipMemsetAsync(cnt, 0, sizeof(int), stream);

    // pregate table: G[v][:] = relu(embed[v]) @ W_ih^T + b_ih + b_hh
    gemm_nt<true, false><<<dim3(16, 32, 1), 256, 0, stream>>>(
        embed, E_, 0, W_ih, E_, 0, b_ih, b_hh, G, G4_, 0, V_, G4_, E_);

    // ---- Phase 1: persistent serial LSTM recurrence ----
    decoder_persistent<<<NBLK, 256, 0, stream>>>(seq, G, W_hh, hT_a, hT_b, hbuf, cnt);

    // ---- Phase 2: batched over all 9600 (t,b) rows ----
    gemm_nt<false, false><<<dim3(150, 8, 1), 256, 0, stream>>>(
        hbuf, H_, 0, W_hm, H_, 0, nullptr, nullptr, mapped, H_, 0, B_ * T_, H_, H_);
    gemm_nt<false, false><<<dim3(3, 4, 64), 256, 0, stream>>>(
        mapped, (size_t)B_ * H_, H_,
        cnn, H_, (size_t)L_ * H_,
        nullptr, nullptr,
        attb, L_, (size_t)T_ * L_, T_, L_, H_);
    att_softmax<<<(B_ * T_ + 3) / 4, 256, 0, stream>>>(attb, B_ * T_);
    gemm_nn<<<dim3(3, 8, 64), 256, 0, stream>>>(
        attb, L_, (size_t)T_ * L_,
        cnn, H_, (size_t)L_ * H_,
        mapped, (size_t)B_ * H_, H_, T_, H_, L_);
    gemm_cat<<<dim3(150, 8, 1), 256, 0, stream>>>(
        mapped, hbuf, W_om, outv, B_ * T_, H_);
    gemm_nt<false, true><<<dim3(150, 16, 1), 256, 0, stream>>>(
        outv, H_, 0, W_logit, H_, 0, b_logit, nullptr, out, V_, 0, B_ * T_, V_, H_);
    logsoftmax_k<<<B_ * T_, 256, 0, stream>>>(out);
}

// Round 7
// 4992.822 us; speedup vs baseline: 1.4076x; 1.4076x over previous
//
#include <hip/hip_runtime.h>
#include <math.h>

#define B_  64
#define T_  150
#define L_  256
#define H_  512
#define E_  512
#define V_  1000
#define G4_ 2048   // 4*H

typedef _Float16 half2_t __attribute__((ext_vector_type(2)));

__device__ __forceinline__ float sigmf(float x) { return 1.0f / (1.0f + expf(-x)); }

__device__ __forceinline__ float dot2(unsigned int w, unsigned int h, float acc)
{
#if __has_builtin(__builtin_amdgcn_fdot2)
    return __builtin_amdgcn_fdot2(__builtin_bit_cast(half2_t, w),
                                  __builtin_bit_cast(half2_t, h), acc, false);
#else
    half2_t a = __builtin_bit_cast(half2_t, w);
    half2_t b = __builtin_bit_cast(half2_t, h);
    return acc + (float)a.x * (float)b.x + (float)a.y * (float)b.y;
#endif
}

// ---------------- W_hh fp32 [4H][H] -> packed fp16 Wp[256][1024] of uint2:
// Wp[k2][u] = { half2(W[2u][2k2],W[2u][2k2+1]), half2(W[2u+1][2k2],W[2u+1][2k2+1]) }
__global__ __launch_bounds__(256) void wcvt(
    const float* __restrict__ W, uint2* __restrict__ Wp)
{
    __shared__ uint2 tile[32][33];
    const int u0 = blockIdx.x * 32;   // u tile (row pairs)
    const int k0 = blockIdx.y * 32;   // k2 tile
    const int x = threadIdx.x & 31, y = threadIdx.x >> 5;
    const float2* W2 = (const float2*)W;  // [2048][256]
    for (int i = y; i < 32; i += 8) {
        int u = u0 + i, k2 = k0 + x;
        float2 r0 = W2[(size_t)(2 * u)     * 256 + k2];
        float2 r1 = W2[(size_t)(2 * u + 1) * 256 + k2];
        half2_t h0; h0.x = (_Float16)r0.x; h0.y = (_Float16)r0.y;
        half2_t h1; h1.x = (_Float16)r1.x; h1.y = (_Float16)r1.y;
        uint2 p;
        p.x = __builtin_bit_cast(unsigned int, h0);
        p.y = __builtin_bit_cast(unsigned int, h1);
        tile[i][x] = p;
    }
    __syncthreads();
    for (int i = y; i < 32; i += 8) {
        Wp[(size_t)(k0 + i) * 1024 + u0 + x] = tile[x][i];
    }
}

// ---------------- batch-split serial LSTM: 32 blocks x 2 batch elems, NO grid sync.
// h, c, gates all block-local in LDS; W_hh fp16 streams from (XCD-resident) L2.
// Thread tid owns gate cols {2tid, 2tid+1} for both b's; dot2 over packed k-pairs.
__global__ __launch_bounds__(1024) void decoder_batch(
    const int*   __restrict__ seq,    // [B][T]
    const float* __restrict__ G,      // [V][4H] pregate table (fp32)
    const uint2* __restrict__ Wp,     // [256][1024] packed fp16
    float* __restrict__ hbuf)         // rows (t,b): [T*B][H]
{
    const int tid = threadIdx.x;
    const int b0  = blockIdx.x * 2;

    __shared__ float gsh[G4_][2];     // gates [col][bb]   16 KB
    __shared__ float csh[2][H_];      // c-state           4 KB
    __shared__ uint2 hpk[H_ / 2];     // h packed fp16: .x=b0 pair, .y=b1 pair
    __shared__ int   sq[2][T_];

    if (tid < 2 * T_) sq[tid / T_][tid % T_] = seq[(b0 + tid / T_) * T_ + tid % T_];
    if (tid < H_ / 2) { uint2 z; z.x = 0u; z.y = 0u; hpk[tid] = z; }
    if (tid < H_) { csh[0][tid] = 0.f; csh[1][tid] = 0.f; }
    __syncthreads();

    const int c0 = 2 * tid;
    // step-0 pregate
    float2 ga = *(const float2*)(G + (size_t)sq[0][0] * G4_ + c0);
    float2 gb = *(const float2*)(G + (size_t)sq[1][0] * G4_ + c0);

    const uint2* wp = Wp + tid;

    for (int t = 0; t < T_; ++t) {
        float a00 = ga.x, a10 = ga.y;   // colA/colB for b0
        float a01 = gb.x, a11 = gb.y;   // colA/colB for b1
        #pragma unroll 8
        for (int k2 = 0; k2 < 256; ++k2) {
            uint2 wv = wp[(size_t)k2 * 1024];   // 8B coalesced, L2-resident
            uint2 hv = hpk[k2];                 // LDS broadcast
            a00 = dot2(wv.x, hv.x, a00);
            a01 = dot2(wv.x, hv.y, a01);
            a10 = dot2(wv.y, hv.x, a10);
            a11 = dot2(wv.y, hv.y, a11);
        }
        // prefetch next step's pregate (independent of h)
        if (t + 1 < T_) {
            ga = *(const float2*)(G + (size_t)sq[0][t + 1] * G4_ + c0);
            gb = *(const float2*)(G + (size_t)sq[1][t + 1] * G4_ + c0);
        }
        *(float2*)&gsh[c0][0]     = make_float2(a00, a01);
        *(float2*)&gsh[c0 + 1][0] = make_float2(a10, a11);
        __syncthreads();

        // ---- cell: thread (j = tid&511, bb = tid>>9)
        {
            const int j = tid & (H_ - 1), bb = tid >> 9;
            float gi = gsh[j][bb];
            float gf = gsh[H_ + j][bb];
            float gg = gsh[2 * H_ + j][bb];
            float go = gsh[3 * H_ + j][bb];
            float c2 = sigmf(gf) * csh[bb][j] + sigmf(gi) * tanhf(gg);
            float h2 = sigmf(go) * tanhf(c2);
            csh[bb][j] = c2;
            hbuf[((size_t)t * 64 + b0 + bb) * H_ + j] = h2;
            ((_Float16*)&hpk[j >> 1])[bb * 2 + (j & 1)] = (_Float16)h2;
        }
        __syncthreads();
    }
}

// ---------------- generic NT GEMM: C[M][N] = op(A[M][K]) @ B[N][K]^T (+bias)
template<bool RELU_A, bool REMAP>
__global__ __launch_bounds__(256) void gemm_nt(
    const float* __restrict__ A, size_t lda, size_t azs,
    const float* __restrict__ Bm, size_t ldb, size_t bzs,
    const float* __restrict__ bias1, const float* __restrict__ bias2,
    float* __restrict__ C, size_t ldc, size_t czs, int M, int N, int K)
{
    A  += blockIdx.z * azs;
    Bm += blockIdx.z * bzs;
    C  += blockIdx.z * czs;
    __shared__ __align__(16) float As[16][68];
    __shared__ __align__(16) float Bs[16][68];
    const int tid = threadIdx.x;
    const int m0 = blockIdx.x * 64;
    const int n0 = blockIdx.y * 64;
    const int lr = tid >> 2;
    const int lc = (tid & 3) << 2;
    const int tm = (tid & 15) << 2;
    const int tn = (tid >> 4) << 2;
    float acc[4][4] = {};

    for (int kb = 0; kb < K; kb += 16) {
        float4 a4 = make_float4(0.f, 0.f, 0.f, 0.f);
        int gm = m0 + lr;
        if (gm < M) a4 = *(const float4*)(A + (size_t)gm * lda + kb + lc);
        if (RELU_A) {
            a4.x = fmaxf(a4.x, 0.f); a4.y = fmaxf(a4.y, 0.f);
            a4.z = fmaxf(a4.z, 0.f); a4.w = fmaxf(a4.w, 0.f);
        }
        As[lc + 0][lr] = a4.x; As[lc + 1][lr] = a4.y;
        As[lc + 2][lr] = a4.z; As[lc + 3][lr] = a4.w;

        float4 b4 = make_float4(0.f, 0.f, 0.f, 0.f);
        int gn = n0 + lr;
        if (gn < N) b4 = *(const float4*)(Bm + (size_t)gn * ldb + kb + lc);
        Bs[lc + 0][lr] = b4.x; Bs[lc + 1][lr] = b4.y;
        Bs[lc + 2][lr] = b4.z; Bs[lc + 3][lr] = b4.w;
        __syncthreads();

        #pragma unroll
        for (int k = 0; k < 16; ++k) {
            float4 av = *(const float4*)&As[k][tm];
            float4 bv = *(const float4*)&Bs[k][tn];
            float af[4] = {av.x, av.y, av.z, av.w};
            float bf[4] = {bv.x, bv.y, bv.z, bv.w};
            #pragma unroll
            for (int i = 0; i < 4; ++i)
                #pragma unroll
                for (int j = 0; j < 4; ++j)
                    acc[i][j] += af[i] * bf[j];
        }
        __syncthreads();
    }

    #pragma unroll
    for (int i = 0; i < 4; ++i) {
        int gm = m0 + tm + i;
        if (gm >= M) continue;
        size_t row = REMAP ? ((size_t)(gm & 63) * T_ + (gm >> 6)) : (size_t)gm;
        #pragma unroll
        for (int j = 0; j < 4; ++j) {
            int gn = n0 + tn + j;
            if (gn >= N) continue;
            float v = acc[i][j];
            if (bias1) v += bias1[gn];
            if (bias2) v += bias2[gn];
            C[row * ldc + gn] = v;
        }
    }
}

// ---------------- dual-A NT GEMM: C[M][N] = [A1|A2] @ Bm[N][1024]^T
__global__ __launch_bounds__(256) void gemm_cat(
    const float* __restrict__ A1, const float* __restrict__ A2,
    const float* __restrict__ Bm, float* __restrict__ C, int M, int N)
{
    __shared__ __align__(16) float As[16][68];
    __shared__ __align__(16) float Bs[16][68];
    const int tid = threadIdx.x;
    const int m0 = blockIdx.x * 64;
    const int n0 = blockIdx.y * 64;
    const int lr = tid >> 2;
    const int lc = (tid & 3) << 2;
    const int tm = (tid & 15) << 2;
    const int tn = (tid >> 4) << 2;
    float acc[4][4] = {};

    for (int kb = 0; kb < 1024; kb += 16) {
        const float* Asel = (kb < 512) ? A1 : A2;
        int kk = kb & 511;
        float4 a4 = make_float4(0.f, 0.f, 0.f, 0.f);
        int gm = m0 + lr;
        if (gm < M) a4 = *(const float4*)(Asel + (size_t)gm * 512 + kk + lc);
        As[lc + 0][lr] = a4.x; As[lc + 1][lr] = a4.y;
        As[lc + 2][lr] = a4.z; As[lc + 3][lr] = a4.w;

        float4 b4 = make_float4(0.f, 0.f, 0.f, 0.f);
        int gn = n0 + lr;
        if (gn < N) b4 = *(const float4*)(Bm + (size_t)gn * 1024 + kb + lc);
        Bs[lc + 0][lr] = b4.x; Bs[lc + 1][lr] = b4.y;
        Bs[lc + 2][lr] = b4.z; Bs[lc + 3][lr] = b4.w;
        __syncthreads();

        #pragma unroll
        for (int k = 0; k < 16; ++k) {
            float4 av = *(const float4*)&As[k][tm];
            float4 bv = *(const float4*)&Bs[k][tn];
            float af[4] = {av.x, av.y, av.z, av.w};
            float bf[4] = {bv.x, bv.y, bv.z, bv.w};
            #pragma unroll
            for (int i = 0; i < 4; ++i)
                #pragma unroll
                for (int j = 0; j < 4; ++j)
                    acc[i][j] += af[i] * bf[j];
        }
        __syncthreads();
    }

    #pragma unroll
    for (int i = 0; i < 4; ++i) {
        int gm = m0 + tm + i;
        if (gm >= M) continue;
        #pragma unroll
        for (int j = 0; j < 4; ++j) {
            int gn = n0 + tn + j;
            if (gn >= N) continue;
            C[(size_t)gm * N + gn] = acc[i][j];
        }
    }
}

// ---------------- NN GEMM: C[M][N] = A[M][K] @ B[K][N]  (ctx = att @ cnn)
__global__ __launch_bounds__(256) void gemm_nn(
    const float* __restrict__ A, size_t lda, size_t azs,
    const float* __restrict__ Bm, size_t ldb, size_t bzs,
    float* __restrict__ C, size_t ldc, size_t czs, int M, int N, int K)
{
    A  += blockIdx.z * azs;
    Bm += blockIdx.z * bzs;
    C  += blockIdx.z * czs;
    __shared__ __align__(16) float As[16][68];
    __shared__ __align__(16) float Bs[16][68];
    const int tid = threadIdx.x;
    const int m0 = blockIdx.x * 64;
    const int n0 = blockIdx.y * 64;
    const int lr = tid >> 2;
    const int lc = (tid & 3) << 2;
    const int br = tid >> 4;
    const int bc = (tid & 15) << 2;
    const int tm = (tid & 15) << 2;
    const int tn = (tid >> 4) << 2;
    float acc[4][4] = {};

    for (int kb = 0; kb < K; kb += 16) {
        float4 a4 = make_float4(0.f, 0.f, 0.f, 0.f);
        int gm = m0 + lr;
        if (gm < M) a4 = *(const float4*)(A + (size_t)gm * lda + kb + lc);
        As[lc + 0][lr] = a4.x; As[lc + 1][lr] = a4.y;
        As[lc + 2][lr] = a4.z; As[lc + 3][lr] = a4.w;

        float4 b4 = make_float4(0.f, 0.f, 0.f, 0.f);
        if (n0 + bc < N) b4 = *(const float4*)(Bm + (size_t)(kb + br) * ldb + n0 + bc);
        Bs[br][bc + 0] = b4.x; Bs[br][bc + 1] = b4.y;
        Bs[br][bc + 2] = b4.z; Bs[br][bc + 3] = b4.w;
        __syncthreads();

        #pragma unroll
        for (int k = 0; k < 16; ++k) {
            float4 av = *(const float4*)&As[k][tm];
            float4 bv = *(const float4*)&Bs[k][tn];
            float af[4] = {av.x, av.y, av.z, av.w};
            float bf[4] = {bv.x, bv.y, bv.z, bv.w};
            #pragma unroll
            for (int i = 0; i < 4; ++i)
                #pragma unroll
                for (int j = 0; j < 4; ++j)
                    acc[i][j] += af[i] * bf[j];
        }
        __syncthreads();
    }

    #pragma unroll
    for (int i = 0; i < 4; ++i) {
        int gm = m0 + tm + i;
        if (gm >= M) continue;
        #pragma unroll
        for (int j = 0; j < 4; ++j) {
            int gn = n0 + tn + j;
            if (gn >= N) continue;
            C[(size_t)gm * ldc + gn] = acc[i][j];
        }
    }
}

// ---------------- softmax over rows of 256 (attention weights), 4 rows/block
__global__ __launch_bounds__(256) void att_softmax(float* __restrict__ att, int nrows)
{
    const int tid = threadIdx.x, lane = tid & 63, wave = tid >> 6;
    const int row = blockIdx.x * 4 + wave;
    if (row >= nrows) return;
    float4* p = (float4*)(att + (size_t)row * L_);
    float4 sc = p[lane];
    float mx = fmaxf(fmaxf(sc.x, sc.y), fmaxf(sc.z, sc.w));
    #pragma unroll
    for (int off = 32; off; off >>= 1) mx = fmaxf(mx, __shfl_xor(mx, off));
    float e0 = expf(sc.x - mx), e1 = expf(sc.y - mx);
    float e2 = expf(sc.z - mx), e3 = expf(sc.w - mx);
    float s = e0 + e1 + e2 + e3;
    #pragma unroll
    for (int off = 32; off; off >>= 1) s += __shfl_xor(s, off);
    float inv = 1.f / s;
    p[lane] = make_float4(e0 * inv, e1 * inv, e2 * inv, e3 * inv);
}

// ---------------- per-row log_softmax over V=1000, in place
__global__ __launch_bounds__(256) void logsoftmax_k(float* __restrict__ out)
{
    const int row = blockIdx.x;
    float* p = out + (size_t)row * V_;
    const int tid = threadIdx.x, lane = tid & 63, wave = tid >> 6;
    __shared__ float red[8];

    float vals[4];
    int n = 0;
    float mx = -INFINITY;
    for (int v = tid; v < V_; v += 256) { vals[n] = p[v]; mx = fmaxf(mx, vals[n]); ++n; }
    #pragma unroll
    for (int off = 32; off; off >>= 1) mx = fmaxf(mx, __shfl_xor(mx, off));
    if (lane == 0) red[wave] = mx;
    __syncthreads();
    mx = fmaxf(fmaxf(red[0], red[1]), fmaxf(red[2], red[3]));

    float s = 0.f;
    for (int i = 0; i < n; ++i) s += expf(vals[i] - mx);
    #pragma unroll
    for (int off = 32; off; off >>= 1) s += __shfl_xor(s, off);
    if (lane == 0) red[4 + wave] = s;
    __syncthreads();
    s = red[4] + red[5] + red[6] + red[7];

    const float lse = mx + logf(s);
    n = 0;
    for (int v = tid; v < V_; v += 256) { p[v] = vals[n] - lse; ++n; }
}

extern "C" void kernel_launch(void* const* d_in, const int* in_sizes, int n_in,
                              void* d_out, int out_size, void* d_ws, size_t ws_size,
                              hipStream_t stream)
{
    const float* cnn     = (const float*)d_in[0];
    const int*   seq     = (const int*)d_in[1];
    const float* embed   = (const float*)d_in[2];
    const float* W_ih    = (const float*)d_in[3];
    const float* b_ih    = (const float*)d_in[4];
    const float* W_hh    = (const float*)d_in[5];
    const float* b_hh    = (const float*)d_in[6];
    const float* W_hm    = (const float*)d_in[7];
    const float* W_om    = (const float*)d_in[8];
    const float* W_logit = (const float*)d_in[9];
    const float* b_logit = (const float*)d_in[10];
    float* out = (float*)d_out;

    float* ws = (float*)d_ws;
    float* G    = ws;                                  // 1000*2048 = 2,048,000
    float* hbuf = G + (size_t)V_ * G4_;                // 9600*512 (rows (t,b))
    float* outv = hbuf + (size_t)B_ * T_ * H_;         // 9600*512
    // scratch inside d_out (dead before the final logits write):
    float* mapped = out;                               // 9600*512; reused as ctx
    float* attb   = out + (size_t)B_ * T_ * H_;        // 9600*256
    uint2* Wp     = (uint2*)(out + (size_t)B_ * T_ * H_ + (size_t)B_ * T_ * L_); // 2 MB

    // pregate table: G[v][:] = relu(embed[v]) @ W_ih^T + b_ih + b_hh
    gemm_nt<true, false><<<dim3(16, 32, 1), 256, 0, stream>>>(
        embed, E_, 0, W_ih, E_, 0, b_ih, b_hh, G, G4_, 0, V_, G4_, E_);
    // W_hh -> packed fp16 (L2-resident 2 MB stream)
    wcvt<<<dim3(32, 8), 256, 0, stream>>>(W_hh, Wp);

    // ---- Phase 1: batch-split serial LSTM (no grid sync at all) ----
    decoder_batch<<<32, 1024, 0, stream>>>(seq, G, Wp, hbuf);

    // ---- Phase 2: batched over all 9600 (t,b) rows ----
    gemm_nt<false, false><<<dim3(150, 8, 1), 256, 0, stream>>>(
        hbuf, H_, 0, W_hm, H_, 0, nullptr, nullptr, mapped, H_, 0, B_ * T_, H_, H_);
    gemm_nt<false, false><<<dim3(3, 4, 64), 256, 0, stream>>>(
        mapped, (size_t)B_ * H_, H_,
        cnn, H_, (size_t)L_ * H_,
        nullptr, nullptr,
        attb, L_, (size_t)T_ * L_, T_, L_, H_);
    att_softmax<<<(B_ * T_ + 3) / 4, 256, 0, stream>>>(attb, B_ * T_);
    gemm_nn<<<dim3(3, 8, 64), 256, 0, stream>>>(
        attb, L_, (size_t)T_ * L_,
        cnn, H_, (size_t)L_ * H_,
        mapped, (size_t)B_ * H_, H_, T_, H_, L_);
    gemm_cat<<<dim3(150, 8, 1), 256, 0, stream>>>(
        mapped, hbuf, W_om, outv, B_ * T_, H_);
    gemm_nt<false, true><<<dim3(150, 16, 1), 256, 0, stream>>>(
        outv, H_, 0, W_logit, H_, 0, b_logit, nullptr, out, V_, 0, B_ * T_, V_, H_);
    logsoftmax_k<<<B_ * T_, 256, 0, stream>>>(out);
}